// Round 1
// baseline (571.317 us; speedup 1.0000x reference)
//
#include <hip/hip_runtime.h>
#include <hip/hip_bf16.h>

// Problem constants
#define N_IN  2048
#define N_HID 4096
#define N_OUT 1024
#define N_TOT 7168
#define BATCH 4096
#define LDA2  (N_IN + N_HID)   // 6144: [x | H] activation buffer leading dim
#define OUT_ELEMS ((size_t)BATCH * N_OUT)
#define BUF 16384              // shorts per 256x64 bf16 tile (32 KiB)

typedef __attribute__((ext_vector_type(8))) short short8;
typedef __attribute__((ext_vector_type(4))) float f32x4;

static __device__ __forceinline__ unsigned short f2bf(float f) {
  __hip_bfloat16 h = __float2bfloat16(f);
  return __builtin_bit_cast(unsigned short, h);
}

// ---------------------------------------------------------------------------
// Convert x (BATCH x N_IN fp32) -> bf16 into A2[:, 0:2048] (row stride 6144)
// ---------------------------------------------------------------------------
__global__ void conv_x_kernel(const float* __restrict__ x,
                              unsigned short* __restrict__ A2) {
  int idx = blockIdx.x * 256 + threadIdx.x;     // BATCH*N_IN/4 threads
  int row = idx >> 9;                           // N_IN/4 = 512 groups per row
  int col = (idx & 511) << 2;
  const float4 v = *(const float4*)(x + (size_t)row * N_IN + col);
  ushort4 o;
  o.x = f2bf(v.x); o.y = f2bf(v.y); o.z = f2bf(v.z); o.w = f2bf(v.w);
  *(ushort4*)(A2 + (size_t)row * LDA2 + col) = o;
}

// ---------------------------------------------------------------------------
// Transpose-convert: dst[n][k] = (bf16)src[k][n]
// ---------------------------------------------------------------------------
__global__ void conv_t_kernel(const float* __restrict__ src, int lds_,
                              unsigned short* __restrict__ dst, int ldd) {
  __shared__ float tile[32][33];
  const int t = threadIdx.x;
  const int k0 = blockIdx.y << 5, n0 = blockIdx.x << 5;
  const int r = t >> 3, c = (t & 7) << 2;
  const float4 v = *(const float4*)(src + (size_t)(k0 + r) * lds_ + n0 + c);
  tile[r][c] = v.x; tile[r][c + 1] = v.y; tile[r][c + 2] = v.z; tile[r][c + 3] = v.w;
  __syncthreads();
  ushort4 o;
  o.x = f2bf(tile[c][r]);
  o.y = f2bf(tile[c + 1][r]);
  o.z = f2bf(tile[c + 2][r]);
  o.w = f2bf(tile[c + 3][r]);
  *(ushort4*)(dst + (size_t)(n0 + r) * ldd + k0 + c) = o;
}

// ---------------------------------------------------------------------------
// out = P0 + P1 + P2 + P3 + P4. Fixed order -> deterministic.
// ---------------------------------------------------------------------------
__global__ void add5_kernel(const float* __restrict__ P, float* __restrict__ out) {
  size_t i = ((size_t)blockIdx.x * 256 + threadIdx.x) * 4;
  float4 a = *(const float4*)(P + i);
  float4 b = *(const float4*)(P + OUT_ELEMS + i);
  float4 c = *(const float4*)(P + 2 * OUT_ELEMS + i);
  float4 d = *(const float4*)(P + 3 * OUT_ELEMS + i);
  float4 e = *(const float4*)(P + 4 * OUT_ELEMS + i);
  float4 o;
  o.x = ((a.x + b.x) + (c.x + d.x)) + e.x;
  o.y = ((a.y + b.y) + (c.y + d.y)) + e.y;
  o.z = ((a.z + b.z) + (c.z + d.z)) + e.z;
  o.w = ((a.w + b.w) + (c.w + d.w)) + e.w;
  *(float4*)(out + i) = o;
}

// ===========================================================================
// 256x256 / BK=64 / 8-wave (2M x 4N) / 8-phase GEMM (T2+T3+T4+T5 template).
// Per wave: 128x64 output = acc[8][4] 16x16 frags. LDS = 2 dbuf x (A 256x64 +
// B 256x64) bf16 = 128 KiB -> 1 block/CU. Staging via global_load_lds w=16,
// pre-swizzled global source (chunk ^= row&7) + XOR on ds_read -> <=2-way
// bank (free, m136).
//
// Staging schedule (per iter i, tiles t0=2i (buf0), t1=2i+1 (buf1)),
// one half-tile (2 gload_lds/wave) per phase:
//   P1: A1.h0@t1   (buf1.A last read prev-iter P8; issued after its barrier)
//   P2: A1.h1@t1
//   P3: B0.h0@t0+2 (b(t0) consumed P1)
//   P4: B0.h1@t0+2  + vmcnt(4): retires {prev P7/P8 = b(t1)} + {P1/P2 = a(t1)}
//                     -> P5 reads valid; leaves P3/P4 in flight
//   P5: A0.h0@t0+2 (a(t0) consumed P1-P4)
//   P6: A0.h1@t0+2
//   P7: B1.h0@t1+2 (b(t1) consumed P5)
//   P8: B1.h1@t1+2  + vmcnt(4): retires P3..P6 = next iter's t0 data;
//                     leaves P7/P8 in flight
// Epilogue iter: P1/P2 stage a(last tile) only; P4 drains vmcnt(0).
// Waits always precede the barrier so cross-wave staging is covered.
// ===========================================================================
struct KCtx {
  int wave, wm, wn, lm, quad, xr, srow, arow, brow;
};

static __device__ __forceinline__ void kctx_init(KCtx& c, int tid) {
  c.wave = tid >> 6;
  c.wm   = c.wave >> 2;          // 0..1 : 128-row half of C
  c.wn   = c.wave & 3;           // 0..3 : 64-col slice of C
  c.lm   = tid & 15;
  c.quad = (tid & 63) >> 4;
  c.xr   = c.lm & 7;
  c.srow = c.wave * 16;          // staging row base within a 128-row half
  c.arow = (c.wm * 128 + c.lm) * 64;
  c.brow = (c.wn * 64  + c.lm) * 64;
}

#define GLDS(GP, LP) __builtin_amdgcn_global_load_lds( \
    (const __attribute__((address_space(1))) void*)(GP), \
    (__attribute__((address_space(3))) void*)(LP), 16, 0, 0)

// Stage half-tile H (128 rows) at k-column KC into LBASE. GBASE carries the
// per-lane row (lane>>3) and swizzled column; LDS dest is wave-uniform.
#define STG(GBASE, LD, LBASE, H, KC) do {                                     \
    GLDS((GBASE) + (size_t)((H)*128 + c.srow    ) * (LD) + (KC),              \
         (LBASE) + ((H)*128 + c.srow    ) * 64);                              \
    GLDS((GBASE) + (size_t)((H)*128 + c.srow + 8) * (LD) + (KC),              \
         (LBASE) + ((H)*128 + c.srow + 8) * 64);                              \
  } while (0)

#define LDB(BB) do {                                                          \
    _Pragma("unroll") for (int nt = 0; nt < 4; ++nt)                          \
    _Pragma("unroll") for (int kk = 0; kk < 2; ++kk)                          \
      bv[nt][kk] = *(const short8*)((BB) + c.brow + nt * 1024 +               \
                                    (((kk * 4 + c.quad) ^ c.xr) << 3));       \
  } while (0)

#define LDA_(AB, Q) do {                                                      \
    _Pragma("unroll") for (int j = 0; j < 2; ++j)                             \
    _Pragma("unroll") for (int kk = 0; kk < 2; ++kk)                          \
      av[j][kk] = *(const short8*)((AB) + c.arow + (2 * (Q) + j) * 1024 +     \
                                   (((kk * 4 + c.quad) ^ c.xr) << 3));        \
  } while (0)

#define MM(Q) do {                                                            \
    _Pragma("unroll") for (int kk = 0; kk < 2; ++kk)                          \
    _Pragma("unroll") for (int j = 0; j < 2; ++j)                             \
    _Pragma("unroll") for (int nt = 0; nt < 4; ++nt)                          \
      acc[2 * (Q) + j][nt] = __builtin_amdgcn_mfma_f32_16x16x32_bf16(         \
          av[j][kk], bv[nt][kk], acc[2 * (Q) + j][nt], 0, 0, 0);              \
  } while (0)

#define BAR       __builtin_amdgcn_s_barrier()
#define WAITLGKM  asm volatile("s_waitcnt lgkmcnt(0)" ::: "memory")
#define WAITVM4   asm volatile("s_waitcnt vmcnt(4)" ::: "memory")
#define WAITVM0   asm volatile("s_waitcnt vmcnt(0)" ::: "memory")
#define PRIO1     __builtin_amdgcn_s_setprio(1)
#define PRIO0     __builtin_amdgcn_s_setprio(0)

static __device__ __forceinline__ void kloop_256(
    const unsigned short* __restrict__ Agl,   // A + (rowb + lane>>3)*lda + gcol
    const unsigned short* __restrict__ Bgl,
    const int lda, const int ldb, const int kiters,  // kiters = K/128, >= 2
    unsigned short* __restrict__ S, const KCtx& c, f32x4 acc[8][4]) {
  unsigned short* const A0 = S;
  unsigned short* const A1 = S + BUF;
  unsigned short* const B0 = S + 2 * BUF;
  unsigned short* const B1 = S + 3 * BUF;

  short8 bv[4][2], av[2][2];

  // prologue: a(0), b(0), b(1); wait all but b(1)'s 4 calls
  STG(Agl, lda, A0, 0, 0); STG(Agl, lda, A0, 1, 0);
  STG(Bgl, ldb, B0, 0, 0); STG(Bgl, ldb, B0, 1, 0);
  STG(Bgl, ldb, B1, 0, 64); STG(Bgl, ldb, B1, 1, 64);
  WAITVM4;
  BAR;

#pragma unroll 1
  for (int i = 0; i < kiters - 1; ++i) {
    const int k1 = i * 128 + 64, k2 = i * 128 + 128, k3 = i * 128 + 192;
    // P1..P4: tile t0 (buf0)
    LDB(B0); LDA_(A0, 0); STG(Agl, lda, A1, 0, k1);
    BAR; WAITLGKM; PRIO1; MM(0); PRIO0; BAR;
    LDA_(A0, 1); STG(Agl, lda, A1, 1, k1);
    BAR; WAITLGKM; PRIO1; MM(1); PRIO0; BAR;
    LDA_(A0, 2); STG(Bgl, ldb, B0, 0, k2);
    BAR; WAITLGKM; PRIO1; MM(2); PRIO0; BAR;
    LDA_(A0, 3); STG(Bgl, ldb, B0, 1, k2);
    WAITVM4; BAR; WAITLGKM; PRIO1; MM(3); PRIO0; BAR;
    // P5..P8: tile t1 (buf1)
    LDB(B1); LDA_(A1, 0); STG(Agl, lda, A0, 0, k2);
    BAR; WAITLGKM; PRIO1; MM(0); PRIO0; BAR;
    LDA_(A1, 1); STG(Agl, lda, A0, 1, k2);
    BAR; WAITLGKM; PRIO1; MM(1); PRIO0; BAR;
    LDA_(A1, 2); STG(Bgl, ldb, B1, 0, k3);
    BAR; WAITLGKM; PRIO1; MM(2); PRIO0; BAR;
    LDA_(A1, 3); STG(Bgl, ldb, B1, 1, k3);
    WAITVM4; BAR; WAITLGKM; PRIO1; MM(3); PRIO0; BAR;
  }
  // epilogue iteration: tiles 2*kiters-2 (buf0), 2*kiters-1 (buf1)
  {
    const int k1 = (kiters - 1) * 128 + 64;
    LDB(B0); LDA_(A0, 0); STG(Agl, lda, A1, 0, k1);
    BAR; WAITLGKM; PRIO1; MM(0); PRIO0; BAR;
    LDA_(A0, 1); STG(Agl, lda, A1, 1, k1);
    BAR; WAITLGKM; PRIO1; MM(1); PRIO0; BAR;
    LDA_(A0, 2);
    BAR; WAITLGKM; PRIO1; MM(2); PRIO0; BAR;
    LDA_(A0, 3);
    WAITVM0; BAR; WAITLGKM; PRIO1; MM(3); PRIO0; BAR;
    LDB(B1); LDA_(A1, 0);
    BAR; WAITLGKM; PRIO1; MM(0); PRIO0; BAR;
    LDA_(A1, 1);
    BAR; WAITLGKM; PRIO1; MM(1); PRIO0; BAR;
    LDA_(A1, 2);
    BAR; WAITLGKM; PRIO1; MM(2); PRIO0; BAR;
    LDA_(A1, 3);
    BAR; WAITLGKM; PRIO1; MM(3); PRIO0; BAR;
  }
}

// ---------------------------------------------------------------------------
// Epilogue: 4 passes of 64 rows through LDS (fp32, stride 260 -> <=2-way
// banks), coalesced copy-out: float4 (fp32) or relu+cvt short4 (bf16).
// ---------------------------------------------------------------------------
template <bool TO_BF16_RELU>
static __device__ __forceinline__ void epi_store(
    unsigned short* __restrict__ S, const KCtx& c, int tid, f32x4 acc[8][4],
    void* __restrict__ Cout, int ldc, int rowb, int colb) {
  float* Cf = (float*)S;
#pragma unroll 1
  for (int p = 0; p < 4; ++p) {
    if (c.wm == (p >> 1)) {
      const int mtb = (p & 1) * 4;
#pragma unroll
      for (int mt = 0; mt < 4; ++mt)
#pragma unroll
        for (int nt = 0; nt < 4; ++nt)
#pragma unroll
          for (int r = 0; r < 4; ++r)
            Cf[(mt * 16 + c.quad * 4 + r) * 260 + c.wn * 64 + nt * 16 + c.lm] =
                acc[mtb + mt][nt][r];
    }
    __syncthreads();
    const int c4 = (tid & 63) * 4;
    const int r0 = tid >> 6;
#pragma unroll
    for (int j = 0; j < 8; ++j) {
      const int row = r0 + 8 * j;
      float4 v = *(const float4*)(Cf + row * 260 + c4);
      if (TO_BF16_RELU) {
        ushort4 o;
        o.x = f2bf(v.x > 0.f ? v.x : 0.f);
        o.y = f2bf(v.y > 0.f ? v.y : 0.f);
        o.z = f2bf(v.z > 0.f ? v.z : 0.f);
        o.w = f2bf(v.w > 0.f ? v.w : 0.f);
        *(ushort4*)((unsigned short*)Cout +
                    (size_t)(rowb + p * 64 + row) * ldc + colb + c4) = o;
      } else {
        *(float4*)((float*)Cout +
                   (size_t)(rowb + p * 64 + row) * ldc + colb + c4) = v;
      }
    }
    __syncthreads();
  }
}

// ---------------------------------------------------------------------------
// Fused GEMM1: [H | P0] = relu_split(x2 @ [W1 | W2]). grid (20, 16), 512 thr.
// bn<16 -> relu+bf16 into A2[:,2048+bn*256..]; bn>=16 -> fp32 into P0.
// ---------------------------------------------------------------------------
__global__ __launch_bounds__(512, 2)
void gemm_fused2(const unsigned short* __restrict__ A,
                 const unsigned short* __restrict__ Bt,
                 unsigned short* __restrict__ Hout,
                 float* __restrict__ P0) {
  __shared__ __align__(16) unsigned short S[4 * BUF];  // 128 KiB
  const int tid = threadIdx.x;
  const int lane = tid & 63;
  KCtx c; kctx_init(c, tid);
  const int bm = blockIdx.y, bn = blockIdx.x;
  const int gcol = ((lane & 7) ^ (lane >> 3)) << 3;   // pre-swizzled 16B chunk

  const unsigned short* Agl = A  + (size_t)(bm * 256 + (lane >> 3)) * LDA2 + gcol;
  const unsigned short* Bgl = Bt + (size_t)(bn * 256 + (lane >> 3)) * N_IN + gcol;

  f32x4 acc[8][4];
#pragma unroll
  for (int i = 0; i < 8; ++i)
#pragma unroll
    for (int j = 0; j < 4; ++j)
      acc[i][j] = (f32x4){0.f, 0.f, 0.f, 0.f};

  kloop_256(Agl, Bgl, LDA2, N_IN, N_IN / 128, S, c, acc);
  __syncthreads();   // all K-loop LDS traffic done before smem reuse

  if (bn < 16)
    epi_store<true >(S, c, tid, acc, Hout, LDA2, bm * 256, bn * 256);
  else
    epi_store<false>(S, c, tid, acc, P0, N_OUT, bm * 256, (bn - 16) * 256);
}

// ---------------------------------------------------------------------------
// GEMM2: P[1+z] = H[:, z*1024:(z+1)*1024] @ W3-slice. grid (4, 16, 4) = 256
// blocks (one full CU round). Single-writer partials -> deterministic.
// ---------------------------------------------------------------------------
__global__ __launch_bounds__(512, 2)
void gemm_p2(const unsigned short* __restrict__ A,
             const unsigned short* __restrict__ Bt,
             float* __restrict__ P) {
  __shared__ __align__(16) unsigned short S[4 * BUF];
  const int tid = threadIdx.x;
  const int lane = tid & 63;
  KCtx c; kctx_init(c, tid);
  const int bm = blockIdx.y, bn = blockIdx.x;
  const int ko0 = blockIdx.z * 1024;
  const int gcol = ((lane & 7) ^ (lane >> 3)) << 3;

  const unsigned short* Agl = A  + (size_t)(bm * 256 + (lane >> 3)) * LDA2 + gcol + ko0;
  const unsigned short* Bgl = Bt + (size_t)(bn * 256 + (lane >> 3)) * N_HID + gcol + ko0;

  f32x4 acc[8][4];
#pragma unroll
  for (int i = 0; i < 8; ++i)
#pragma unroll
    for (int j = 0; j < 4; ++j)
      acc[i][j] = (f32x4){0.f, 0.f, 0.f, 0.f};

  kloop_256(Agl, Bgl, LDA2, N_HID, 1024 / 128, S, c, acc);
  __syncthreads();

  epi_store<false>(S, c, tid, acc, P + (size_t)blockIdx.z * OUT_ELEMS, N_OUT,
                   bm * 256, bn * 256);
}

// ---------------------------------------------------------------------------
// kernel_launch
// ws: A2 bf16 4096x6144 (50.3MB) | Bt12 bf16 5120x2048 (21.0MB) |
//     Bt3 bf16 1024x4096 (8.4MB) | P fp32 5 x (4096x1024) (83.9MB) = 163.6MB
// ---------------------------------------------------------------------------
extern "C" void kernel_launch(void* const* d_in, const int* in_sizes, int n_in,
                              void* d_out, int out_size, void* d_ws, size_t ws_size,
                              hipStream_t stream) {
  const float* x = (const float*)d_in[0];
  const float* W = (const float*)d_in[1];

  char* ws = (char*)d_ws;
  const size_t A2_BYTES   = (size_t)BATCH * LDA2 * 2;
  const size_t BT12_BYTES = (size_t)(N_HID + N_OUT) * N_IN * 2;
  const size_t BT3_BYTES  = (size_t)N_OUT * N_HID * 2;
  unsigned short* A2   = (unsigned short*)ws;
  unsigned short* Bt12 = (unsigned short*)(ws + A2_BYTES);
  unsigned short* Bt3  = (unsigned short*)(ws + A2_BYTES + BT12_BYTES);
  float*          P    = (float*)(ws + A2_BYTES + BT12_BYTES + BT3_BYTES);

  // 1) x -> bf16 into A2[:, 0:2048]
  conv_x_kernel<<<(BATCH * N_IN / 4) / 256, 256, 0, stream>>>(x, A2);

  // 2) Bt12[n][k] = W[k][2048+n], k<2048, n<5120  ([W1 | W2]^T)
  conv_t_kernel<<<dim3((N_HID + N_OUT) / 32, N_IN / 32), 256, 0, stream>>>(
      W + N_IN, N_TOT, Bt12, N_IN);

  // 3) Bt3[n][k] = W[2048+k][6144+n], k<4096, n<1024  (W3^T)
  conv_t_kernel<<<dim3(N_OUT / 32, N_HID / 32), 256, 0, stream>>>(
      W + (size_t)N_IN * N_TOT + N_IN + N_HID, N_TOT, Bt3, N_HID);

  // 4) fused: H = relu(x@W1) -> A2[:,2048:], and P0 = x@W2 (fp32)
  gemm_fused2<<<dim3((N_HID + N_OUT) / 256, BATCH / 256), 512, 0, stream>>>(
      A2, Bt12, A2 + N_IN, P);

  // 5) P1..P4 = H @ W3, split-K=4 (256 blocks = one full CU round)
  gemm_p2<<<dim3(N_OUT / 256, BATCH / 256, 4), 512, 0, stream>>>(
      A2 + N_IN, Bt3, P + OUT_ELEMS);

  // 6) out = P0 + P1 + P2 + P3 + P4
  add5_kernel<<<(OUT_ELEMS / 4) / 256, 256, 0, stream>>>(P, (float*)d_out);
}

// Round 2
// 537.883 us; speedup vs baseline: 1.0622x; 1.0622x over previous
//
#include <hip/hip_runtime.h>
#include <hip/hip_bf16.h>

// Problem constants
#define N_IN  2048
#define N_HID 4096
#define N_OUT 1024
#define N_TOT 7168
#define BATCH 4096
#define LDA2  (N_IN + N_HID)   // 6144: [x | H] activation buffer leading dim
#define OUT_ELEMS ((size_t)BATCH * N_OUT)
#define BUF 16384              // shorts per 256x64 bf16 tile (32 KiB)

typedef __attribute__((ext_vector_type(8))) short short8;
typedef __attribute__((ext_vector_type(4))) float f32x4;

static __device__ __forceinline__ unsigned short f2bf(float f) {
  __hip_bfloat16 h = __float2bfloat16(f);
  return __builtin_bit_cast(unsigned short, h);
}

// ---------------------------------------------------------------------------
// Convert x (BATCH x N_IN fp32) -> bf16 into A2[:, 0:2048] (row stride 6144)
// ---------------------------------------------------------------------------
__global__ void conv_x_kernel(const float* __restrict__ x,
                              unsigned short* __restrict__ A2) {
  int idx = blockIdx.x * 256 + threadIdx.x;     // BATCH*N_IN/4 threads
  int row = idx >> 9;                           // N_IN/4 = 512 groups per row
  int col = (idx & 511) << 2;
  const float4 v = *(const float4*)(x + (size_t)row * N_IN + col);
  ushort4 o;
  o.x = f2bf(v.x); o.y = f2bf(v.y); o.z = f2bf(v.z); o.w = f2bf(v.w);
  *(ushort4*)(A2 + (size_t)row * LDA2 + col) = o;
}

// ---------------------------------------------------------------------------
// Transpose-convert: dst[n][k] = (bf16)src[k][n]
// ---------------------------------------------------------------------------
__global__ void conv_t_kernel(const float* __restrict__ src, int lds_,
                              unsigned short* __restrict__ dst, int ldd) {
  __shared__ float tile[32][33];
  const int t = threadIdx.x;
  const int k0 = blockIdx.y << 5, n0 = blockIdx.x << 5;
  const int r = t >> 3, c = (t & 7) << 2;
  const float4 v = *(const float4*)(src + (size_t)(k0 + r) * lds_ + n0 + c);
  tile[r][c] = v.x; tile[r][c + 1] = v.y; tile[r][c + 2] = v.z; tile[r][c + 3] = v.w;
  __syncthreads();
  ushort4 o;
  o.x = f2bf(tile[c][r]);
  o.y = f2bf(tile[c + 1][r]);
  o.z = f2bf(tile[c + 2][r]);
  o.w = f2bf(tile[c + 3][r]);
  *(ushort4*)(dst + (size_t)(n0 + r) * ldd + k0 + c) = o;
}

// ---------------------------------------------------------------------------
// out = P0 + P1 + P2 + P3 (split-K partials). Fixed order -> deterministic.
// ---------------------------------------------------------------------------
__global__ void add4_kernel(const float* __restrict__ P, float* __restrict__ out) {
  size_t i = ((size_t)blockIdx.x * 256 + threadIdx.x) * 4;
  float4 a = *(const float4*)(P + i);
  float4 b = *(const float4*)(P + OUT_ELEMS + i);
  float4 c = *(const float4*)(P + 2 * OUT_ELEMS + i);
  float4 d = *(const float4*)(P + 3 * OUT_ELEMS + i);
  float4 o;
  o.x = (a.x + b.x) + (c.x + d.x);
  o.y = (a.y + b.y) + (c.y + d.y);
  o.z = (a.z + b.z) + (c.z + d.z);
  o.w = (a.w + b.w) + (c.w + d.w);
  *(float4*)(out + i) = o;
}

// ===========================================================================
// 256x256 / BK=64 / 8-wave (2M x 4N) / 8-phase GEMM.
// Round-2 fixes vs round 1:
//   * A0/A1/B0/B1 are SEPARATE __shared__ arrays -> the compiler's LDS-DMA
//     hazard tracking can disambiguate ds_read(X) from in-flight
//     global_load_lds writes to Y != X (single-array forced a conservative
//     vmcnt drain before every phase's ds_read = the round-1 serialization).
//   * STG issued FIRST in each phase, so compiler-inserted per-object waits
//     count the newest loads and resolve to no-stall.
//   * No blanket inline lgkmcnt(0): compiler emits fine-grained lgkm between
//     ds_read and MFMA (m97 asm evidence). Keep raw barriers + counted
//     vmcnt(4) at P4/P8 (never 0 in main loop) + setprio around MFMA.
//
// Ledger (loads per wave; STG = 2 global_load_lds). Main iter i, tiles
// t0=2i (A0,B0), t1=2i+1 (A1,B1):
//   P1: STG A1h0@t1 | read B0 (all), A0 q0
//   P2: STG A1h1@t1 | read A0 q1
//   P3: STG B0h0@t0+2 | read A0 q2     (B0 reads finished in P1; 2-barrier WAR)
//   P4: STG B0h1@t0+2 | read A0 q3; vmcnt(4): outstanding
//       [B1(prev P7/P8), A1(P1/P2), B0(P3/P4)] = 12 -> retires B1+A1 (both
//       consumed at P5), leaves B0's 4 in flight.
//   P5: STG A0h0@t0+2 | read B1 (all), A1 q0
//   P6: STG A0h1@t0+2 | read A1 q1
//   P7: STG B1h0@t1+2 | read A1 q2
//   P8: STG B1h1@t1+2 | read A1 q3; vmcnt(4): outstanding
//       [B0(P3/P4), A0(P5/P6), B1(P7/P8)] = 12 -> retires B0+A0 (consumed
//       next P1), leaves B1's 4.
// Epilogue iter: P1/P2 stage A1 only; P4 drains vmcnt(0). Waits precede the
// pre-MFMA barrier, so cross-wave staging is covered by the rendezvous.
// ===========================================================================
struct KCtx {
  int wave, wm, wn, lm, quad, xr, srow, arow, brow;
};

static __device__ __forceinline__ void kctx_init(KCtx& c, int tid) {
  c.wave = tid >> 6;
  c.wm   = c.wave >> 2;          // 0..1 : 128-row half of C
  c.wn   = c.wave & 3;           // 0..3 : 64-col slice of C
  c.lm   = tid & 15;
  c.quad = (tid & 63) >> 4;
  c.xr   = c.lm & 7;
  c.srow = c.wave * 16;          // staging row base (16 rows per wave)
  c.arow = (c.wm * 128 + c.lm) * 64;
  c.brow = (c.wn * 64  + c.lm) * 64;
}

#define GLDS(GP, LP) __builtin_amdgcn_global_load_lds( \
    (const __attribute__((address_space(1))) void*)(GP), \
    (__attribute__((address_space(3))) void*)(LP), 16, 0, 0)

// Stage half-tile H (128 rows) at k-column KC of the A / B panel.
// Global source is per-lane pre-swizzled (chunk ^= row&7); LDS dest linear.
#define STGA(ARR, H, KC) do {                                                 \
    GLDS(Agl + (size_t)((H)*128 + c.srow    ) * lda + (KC),                   \
         (ARR) + ((H)*128 + c.srow    ) * 64);                                \
    GLDS(Agl + (size_t)((H)*128 + c.srow + 8) * lda + (KC),                   \
         (ARR) + ((H)*128 + c.srow + 8) * 64);                                \
  } while (0)
#define STGB(ARR, H, KC) do {                                                 \
    GLDS(Bgl + (size_t)((H)*128 + c.srow    ) * ldb + (KC),                   \
         (ARR) + ((H)*128 + c.srow    ) * 64);                                \
    GLDS(Bgl + (size_t)((H)*128 + c.srow + 8) * ldb + (KC),                   \
         (ARR) + ((H)*128 + c.srow + 8) * 64);                                \
  } while (0)

#define LDB(BB) do {                                                          \
    _Pragma("unroll") for (int nt = 0; nt < 4; ++nt)                          \
    _Pragma("unroll") for (int kk = 0; kk < 2; ++kk)                          \
      bv[nt][kk] = *(const short8*)((BB) + c.brow + nt * 1024 +               \
                                    (((kk * 4 + c.quad) ^ c.xr) << 3));       \
  } while (0)

#define LDA_(AB, Q) do {                                                      \
    _Pragma("unroll") for (int j = 0; j < 2; ++j)                             \
    _Pragma("unroll") for (int kk = 0; kk < 2; ++kk)                          \
      av[j][kk] = *(const short8*)((AB) + c.arow + (2 * (Q) + j) * 1024 +     \
                                   (((kk * 4 + c.quad) ^ c.xr) << 3));        \
  } while (0)

#define MM(Q) do {                                                            \
    _Pragma("unroll") for (int kk = 0; kk < 2; ++kk)                          \
    _Pragma("unroll") for (int j = 0; j < 2; ++j)                             \
    _Pragma("unroll") for (int nt = 0; nt < 4; ++nt)                          \
      acc[2 * (Q) + j][nt] = __builtin_amdgcn_mfma_f32_16x16x32_bf16(         \
          av[j][kk], bv[nt][kk], acc[2 * (Q) + j][nt], 0, 0, 0);              \
  } while (0)

#define BAR       __builtin_amdgcn_s_barrier()
#define WAITVM4   asm volatile("s_waitcnt vmcnt(4)" ::: "memory")
#define WAITVM0   asm volatile("s_waitcnt vmcnt(0)" ::: "memory")
#define PRIO1     __builtin_amdgcn_s_setprio(1)
#define PRIO0     __builtin_amdgcn_s_setprio(0)

static __device__ __forceinline__ void kloop_256(
    const unsigned short* Agl, const unsigned short* Bgl,
    const int lda, const int ldb, const int kiters,   // kiters = K/128 >= 2
    unsigned short* A0s, unsigned short* A1s,
    unsigned short* B0s, unsigned short* B1s,
    const KCtx& c, f32x4 acc[8][4]) {
  short8 bv[4][2], av[2][2];

  // prologue: a(0), b(0), b(1); retire a(0)+b(0), leave b(1) in flight
  STGA(A0s, 0, 0); STGA(A0s, 1, 0);
  STGB(B0s, 0, 0); STGB(B0s, 1, 0);
  STGB(B1s, 0, 64); STGB(B1s, 1, 64);
  WAITVM4;
  BAR;

#pragma unroll 1
  for (int i = 0; i < kiters - 1; ++i) {
    const int k1 = i * 128 + 64, k2 = i * 128 + 128, k3 = i * 128 + 192;
    // P1..P4: tile t0 (A0,B0)
    STGA(A1s, 0, k1); LDB(B0s); LDA_(A0s, 0);
    BAR; PRIO1; MM(0); PRIO0; BAR;
    STGA(A1s, 1, k1); LDA_(A0s, 1);
    BAR; PRIO1; MM(1); PRIO0; BAR;
    STGB(B0s, 0, k2); LDA_(A0s, 2);
    BAR; PRIO1; MM(2); PRIO0; BAR;
    STGB(B0s, 1, k2); LDA_(A0s, 3);
    WAITVM4;
    BAR; PRIO1; MM(3); PRIO0; BAR;
    // P5..P8: tile t1 (A1,B1)
    STGA(A0s, 0, k2); LDB(B1s); LDA_(A1s, 0);
    BAR; PRIO1; MM(0); PRIO0; BAR;
    STGA(A0s, 1, k2); LDA_(A1s, 1);
    BAR; PRIO1; MM(1); PRIO0; BAR;
    STGB(B1s, 0, k3); LDA_(A1s, 2);
    BAR; PRIO1; MM(2); PRIO0; BAR;
    STGB(B1s, 1, k3); LDA_(A1s, 3);
    WAITVM4;
    BAR; PRIO1; MM(3); PRIO0; BAR;
  }
  // epilogue iteration: tiles 2*kiters-2 (A0,B0), 2*kiters-1 (A1,B1)
  {
    const int kl = (kiters - 1) * 128 + 64;
    STGA(A1s, 0, kl); LDB(B0s); LDA_(A0s, 0);
    BAR; PRIO1; MM(0); PRIO0; BAR;
    STGA(A1s, 1, kl); LDA_(A0s, 1);
    BAR; PRIO1; MM(1); PRIO0; BAR;
    LDA_(A0s, 2);
    BAR; PRIO1; MM(2); PRIO0; BAR;
    LDA_(A0s, 3);
    WAITVM0;                     // drains A1 (needed P5) + leftover B1
    BAR; PRIO1; MM(3); PRIO0; BAR;
    LDB(B1s); LDA_(A1s, 0);
    BAR; PRIO1; MM(0); PRIO0; BAR;
    LDA_(A1s, 1);
    BAR; PRIO1; MM(1); PRIO0; BAR;
    LDA_(A1s, 2);
    BAR; PRIO1; MM(2); PRIO0; BAR;
    LDA_(A1s, 3);
    BAR; PRIO1; MM(3); PRIO0; BAR;
  }
}

// ---------------------------------------------------------------------------
// Epilogue: 16 passes of 16 rows through LDS (fp32, stride 260, reusing B0s:
// 16x260x4B = 16.6 KB <= 32 KB). Coalesced copy-out: float4 (fp32 partials)
// or relu+cvt ushort4 (bf16 H).
// ---------------------------------------------------------------------------
template <bool RELU_BF16>
static __device__ __forceinline__ void epi16(
    unsigned short* B0s, const KCtx& c, int tid, f32x4 acc[8][4],
    void* Cout, int ldc, int rowb, int colb) {
  float* Epi = (float*)B0s;
  const int row = tid >> 6;            // 0..7
  const int col = (tid & 63) * 4;      // 0..252
#pragma unroll 1
  for (int p = 0; p < 16; ++p) {       // pass p covers C rows [p*16, p*16+16)
    if (c.wm == (p >> 3)) {
      const int mt = p & 7;
#pragma unroll
      for (int nt = 0; nt < 4; ++nt)
#pragma unroll
        for (int r = 0; r < 4; ++r)
          Epi[(c.quad * 4 + r) * 260 + c.wn * 64 + nt * 16 + c.lm] =
              acc[mt][nt][r];
    }
    __syncthreads();
#pragma unroll
    for (int j = 0; j < 2; ++j) {
      const int r2 = row + 8 * j;
      float4 v = *(const float4*)(Epi + r2 * 260 + col);
      if (RELU_BF16) {
        ushort4 o;
        o.x = f2bf(v.x > 0.f ? v.x : 0.f);
        o.y = f2bf(v.y > 0.f ? v.y : 0.f);
        o.z = f2bf(v.z > 0.f ? v.z : 0.f);
        o.w = f2bf(v.w > 0.f ? v.w : 0.f);
        *(ushort4*)((unsigned short*)Cout +
                    (size_t)(rowb + p * 16 + r2) * ldc + colb + col) = o;
      } else {
        *(float4*)((float*)Cout +
                   (size_t)(rowb + p * 16 + r2) * ldc + colb + col) = v;
      }
    }
    __syncthreads();
  }
}

// ---------------------------------------------------------------------------
// GEMM1: H = relu(x @ W1), M=4096 N=4096 K=2048. grid (16,16) = 256 blocks
// exactly (one full CU round). Output bf16 into A2[:, 2048:].
// ---------------------------------------------------------------------------
__global__ __launch_bounds__(512, 2)
void gemm1(const unsigned short* __restrict__ A,
           const unsigned short* __restrict__ Bt,
           unsigned short* __restrict__ Hout) {
  __shared__ __align__(16) unsigned short A0s[BUF];
  __shared__ __align__(16) unsigned short A1s[BUF];
  __shared__ __align__(16) unsigned short B0s[BUF];
  __shared__ __align__(16) unsigned short B1s[BUF];
  const int tid = threadIdx.x;
  const int lane = tid & 63;
  KCtx c; kctx_init(c, tid);
  const int bm = blockIdx.y, bn = blockIdx.x;
  const int lda = LDA2, ldb = N_IN;
  const int gcol = ((lane & 7) ^ (lane >> 3)) << 3;   // pre-swizzled 16B chunk

  const unsigned short* Agl = A  + (size_t)(bm * 256 + (lane >> 3)) * lda + gcol;
  const unsigned short* Bgl = Bt + (size_t)(bn * 256 + (lane >> 3)) * ldb + gcol;

  f32x4 acc[8][4];
#pragma unroll
  for (int i = 0; i < 8; ++i)
#pragma unroll
    for (int j = 0; j < 4; ++j)
      acc[i][j] = (f32x4){0.f, 0.f, 0.f, 0.f};

  kloop_256(Agl, Bgl, lda, ldb, N_IN / 128, A0s, A1s, B0s, B1s, c, acc);
  __syncthreads();
  epi16<true>(B0s, c, tid, acc, Hout, LDA2, bm * 256, bn * 256);
}

// ---------------------------------------------------------------------------
// GEMM2: P[z] = A2[:, z*1536:(z+1)*1536] @ W23-slice, z=0..3.
// out = [x|H] @ W[0:6144, 6144:] folded into split-K=4 partials.
// grid (4,16,4) = 256 blocks exactly. Single-writer -> deterministic.
// ---------------------------------------------------------------------------
__global__ __launch_bounds__(512, 2)
void gemm2(const unsigned short* __restrict__ A,
           const unsigned short* __restrict__ Bt,
           float* __restrict__ P) {
  __shared__ __align__(16) unsigned short A0s[BUF];
  __shared__ __align__(16) unsigned short A1s[BUF];
  __shared__ __align__(16) unsigned short B0s[BUF];
  __shared__ __align__(16) unsigned short B1s[BUF];
  const int tid = threadIdx.x;
  const int lane = tid & 63;
  KCtx c; kctx_init(c, tid);
  const int bm = blockIdx.y, bn = blockIdx.x;
  const int ko0 = blockIdx.z * 1536;
  const int lda = LDA2, ldb = LDA2;   // Bt23 is 1024 x 6144
  const int gcol = ((lane & 7) ^ (lane >> 3)) << 3;

  const unsigned short* Agl = A  + (size_t)(bm * 256 + (lane >> 3)) * lda + gcol + ko0;
  const unsigned short* Bgl = Bt + (size_t)(bn * 256 + (lane >> 3)) * ldb + gcol + ko0;

  f32x4 acc[8][4];
#pragma unroll
  for (int i = 0; i < 8; ++i)
#pragma unroll
    for (int j = 0; j < 4; ++j)
      acc[i][j] = (f32x4){0.f, 0.f, 0.f, 0.f};

  kloop_256(Agl, Bgl, lda, ldb, 1536 / 128, A0s, A1s, B0s, B1s, c, acc);
  __syncthreads();
  epi16<false>(B0s, c, tid, acc, P + (size_t)blockIdx.z * OUT_ELEMS, N_OUT,
               bm * 256, bn * 256);
}

// ---------------------------------------------------------------------------
// kernel_launch
// ws: A2 bf16 4096x6144 (50.3MB) | Bt1 bf16 4096x2048 (16.8MB) |
//     Bt23 bf16 1024x6144 (12.6MB) | P fp32 4 x (4096x1024) (67.1MB) = 146.8MB
// ---------------------------------------------------------------------------
extern "C" void kernel_launch(void* const* d_in, const int* in_sizes, int n_in,
                              void* d_out, int out_size, void* d_ws, size_t ws_size,
                              hipStream_t stream) {
  const float* x = (const float*)d_in[0];
  const float* W = (const float*)d_in[1];

  char* ws = (char*)d_ws;
  const size_t A2_BYTES   = (size_t)BATCH * LDA2 * 2;
  const size_t BT1_BYTES  = (size_t)N_HID * N_IN * 2;
  const size_t BT23_BYTES = (size_t)N_OUT * LDA2 * 2;
  unsigned short* A2   = (unsigned short*)ws;
  unsigned short* Bt1  = (unsigned short*)(ws + A2_BYTES);
  unsigned short* Bt23 = (unsigned short*)(ws + A2_BYTES + BT1_BYTES);
  float*          P    = (float*)(ws + A2_BYTES + BT1_BYTES + BT23_BYTES);

  // 1) x -> bf16 into A2[:, 0:2048]
  conv_x_kernel<<<(BATCH * N_IN / 4) / 256, 256, 0, stream>>>(x, A2);

  // 2) Bt1[n][k] = W[k][2048+n], k<2048, n<4096  (W1^T)
  conv_t_kernel<<<dim3(N_HID / 32, N_IN / 32), 256, 0, stream>>>(
      W + N_IN, N_TOT, Bt1, N_IN);

  // 3) Bt23[n][k] = W[k][6144+n], k<6144, n<1024  (W[0:6144, 6144:]^T)
  conv_t_kernel<<<dim3(N_OUT / 32, LDA2 / 32), 256, 0, stream>>>(
      W + N_IN + N_HID, N_TOT, Bt23, LDA2);

  // 4) H = relu(x @ W1) -> A2[:, 2048:]   (grid 256 exact)
  gemm1<<<dim3(N_HID / 256, BATCH / 256), 512, 0, stream>>>(
      A2, Bt1, A2 + N_IN);

  // 5) P0..P3 = [x|H] @ W23, split-K=4   (grid 256 exact)
  gemm2<<<dim3(N_OUT / 256, BATCH / 256, 4), 512, 0, stream>>>(
      A2, Bt23, P);

  // 6) out = P0 + P1 + P2 + P3
  add4_kernel<<<(OUT_ELEMS / 4) / 256, 256, 0, stream>>>(P, (float*)d_out);
}

// Round 3
// 476.872 us; speedup vs baseline: 1.1980x; 1.1279x over previous
//
#include <hip/hip_runtime.h>
#include <hip/hip_bf16.h>

// Problem constants
#define N_IN  2048
#define N_HID 4096
#define N_OUT 1024
#define N_TOT 7168
#define BATCH 4096
#define LDA2  (N_IN + N_HID)   // 6144: [x | H] activation buffer leading dim
#define OUT_ELEMS ((size_t)BATCH * N_OUT)
#define BUF 16384              // shorts per 256x64 bf16 tile (32 KiB)

typedef __attribute__((ext_vector_type(8))) short short8;
typedef __attribute__((ext_vector_type(4))) float f32x4;

static __device__ __forceinline__ unsigned short f2bf(float f) {
  __hip_bfloat16 h = __float2bfloat16(f);
  return __builtin_bit_cast(unsigned short, h);
}

// ---------------------------------------------------------------------------
// Convert x (BATCH x N_IN fp32) -> bf16 into A2[:, 0:2048] (row stride 6144)
// ---------------------------------------------------------------------------
__global__ void conv_x_kernel(const float* __restrict__ x,
                              unsigned short* __restrict__ A2) {
  int idx = blockIdx.x * 256 + threadIdx.x;     // BATCH*N_IN/4 threads
  int row = idx >> 9;                           // N_IN/4 = 512 groups per row
  int col = (idx & 511) << 2;
  const float4 v = *(const float4*)(x + (size_t)row * N_IN + col);
  ushort4 o;
  o.x = f2bf(v.x); o.y = f2bf(v.y); o.z = f2bf(v.z); o.w = f2bf(v.w);
  *(ushort4*)(A2 + (size_t)row * LDA2 + col) = o;
}

// ---------------------------------------------------------------------------
// Transpose-convert: dst[n][k] = (bf16)src[k][n]
// ---------------------------------------------------------------------------
__global__ void conv_t_kernel(const float* __restrict__ src, int lds_,
                              unsigned short* __restrict__ dst, int ldd) {
  __shared__ float tile[32][33];
  const int t = threadIdx.x;
  const int k0 = blockIdx.y << 5, n0 = blockIdx.x << 5;
  const int r = t >> 3, c = (t & 7) << 2;
  const float4 v = *(const float4*)(src + (size_t)(k0 + r) * lds_ + n0 + c);
  tile[r][c] = v.x; tile[r][c + 1] = v.y; tile[r][c + 2] = v.z; tile[r][c + 3] = v.w;
  __syncthreads();
  ushort4 o;
  o.x = f2bf(tile[c][r]);
  o.y = f2bf(tile[c + 1][r]);
  o.z = f2bf(tile[c + 2][r]);
  o.w = f2bf(tile[c + 3][r]);
  *(ushort4*)(dst + (size_t)(n0 + r) * ldd + k0 + c) = o;
}

// ---------------------------------------------------------------------------
// out = P0 + P1 + P2 + P3 (split-K partials). Fixed order -> deterministic.
// ---------------------------------------------------------------------------
__global__ void add4_kernel(const float* __restrict__ P, float* __restrict__ out) {
  size_t i = ((size_t)blockIdx.x * 256 + threadIdx.x) * 4;
  float4 a = *(const float4*)(P + i);
  float4 b = *(const float4*)(P + OUT_ELEMS + i);
  float4 c = *(const float4*)(P + 2 * OUT_ELEMS + i);
  float4 d = *(const float4*)(P + 3 * OUT_ELEMS + i);
  float4 o;
  o.x = (a.x + b.x) + (c.x + d.x);
  o.y = (a.y + b.y) + (c.y + d.y);
  o.z = (a.z + b.z) + (c.z + d.z);
  o.w = (a.w + b.w) + (c.w + d.w);
  *(float4*)(out + i) = o;
}

// ===========================================================================
// 256x256 / BK=64 / 8-wave (2M x 4N) / 8-phase GEMM.
// Round-3 fix: ALL accumulator indices are compile-time constants (rule #20).
// Rounds 1-2 indexed acc[p&7] with a runtime loop var in the epilogue, which
// forced the whole acc[8][4] into scratch (VGPR_Count 116/120 << 176 needed;
// WRITE_SIZE 5x the real output = scratch traffic; MfmaUtil 20%).
//
// Ledger (loads per wave; STG = 2 global_load_lds). Main iter i, tiles
// t0=2i (A0,B0), t1=2i+1 (A1,B1):
//   P1: read B0(all)+A0q0 | STG A1h0@t1
//   P2: read A0q1 | STG A1h1@t1
//   P3: read A0q2 | STG B0h0@t0+2   (B0 reads finished in P1; 2-barrier WAR)
//   P4: read A0q3 | STG B0h1@t0+2; vmcnt(4): outstanding
//       [B1(prev P7/P8), A1(P1/P2), B0(P3/P4)] = 12 -> retires B1+A1 (both
//       consumed at P5), leaves B0's 4 in flight.
//   P5..P8: mirror with A1/B1, staging A0@t0+2, B1@t1+2, vmcnt(4) at P8.
// Epilogue iter: P1/P2 stage A1 only; P4 drains vmcnt(0).
// Waits precede the pre-MFMA barrier, so cross-wave staging is covered.
// ===========================================================================
struct KCtx {
  int wave, wm, wn, lm, quad, xr, srow, arow, brow;
};

static __device__ __forceinline__ void kctx_init(KCtx& c, int tid) {
  c.wave = tid >> 6;
  c.wm   = c.wave >> 2;          // 0..1 : 128-row half of C
  c.wn   = c.wave & 3;           // 0..3 : 64-col slice of C
  c.lm   = tid & 15;
  c.quad = (tid & 63) >> 4;
  c.xr   = c.lm & 7;
  c.srow = c.wave * 16;          // staging row base (16 rows per wave)
  c.arow = (c.wm * 128 + c.lm) * 64;
  c.brow = (c.wn * 64  + c.lm) * 64;
}

#define GLDS(GP, LP) __builtin_amdgcn_global_load_lds( \
    (const __attribute__((address_space(1))) void*)(GP), \
    (__attribute__((address_space(3))) void*)(LP), 16, 0, 0)

// Stage half-tile H (128 rows) at k-column KC of the A / B panel.
// Global source is per-lane pre-swizzled (chunk ^= row&7); LDS dest linear.
#define STGA(ARR, H, KC) do {                                                 \
    GLDS(Agl + (size_t)((H)*128 + c.srow    ) * lda + (KC),                   \
         (ARR) + ((H)*128 + c.srow    ) * 64);                                \
    GLDS(Agl + (size_t)((H)*128 + c.srow + 8) * lda + (KC),                   \
         (ARR) + ((H)*128 + c.srow + 8) * 64);                                \
  } while (0)
#define STGB(ARR, H, KC) do {                                                 \
    GLDS(Bgl + (size_t)((H)*128 + c.srow    ) * ldb + (KC),                   \
         (ARR) + ((H)*128 + c.srow    ) * 64);                                \
    GLDS(Bgl + (size_t)((H)*128 + c.srow + 8) * ldb + (KC),                   \
         (ARR) + ((H)*128 + c.srow + 8) * 64);                                \
  } while (0)

#define LDB(BB) do {                                                          \
    _Pragma("unroll") for (int nt = 0; nt < 4; ++nt)                          \
    _Pragma("unroll") for (int kk = 0; kk < 2; ++kk)                          \
      bv[nt][kk] = *(const short8*)((BB) + c.brow + nt * 1024 +               \
                                    (((kk * 4 + c.quad) ^ c.xr) << 3));       \
  } while (0)

#define LDA_(AB, Q) do {                                                      \
    _Pragma("unroll") for (int j = 0; j < 2; ++j)                             \
    _Pragma("unroll") for (int kk = 0; kk < 2; ++kk)                          \
      av[j][kk] = *(const short8*)((AB) + c.arow + (2 * (Q) + j) * 1024 +     \
                                   (((kk * 4 + c.quad) ^ c.xr) << 3));        \
  } while (0)

#define MM(Q) do {                                                            \
    _Pragma("unroll") for (int kk = 0; kk < 2; ++kk)                          \
    _Pragma("unroll") for (int j = 0; j < 2; ++j)                             \
    _Pragma("unroll") for (int nt = 0; nt < 4; ++nt)                          \
      acc[2 * (Q) + j][nt] = __builtin_amdgcn_mfma_f32_16x16x32_bf16(         \
          av[j][kk], bv[nt][kk], acc[2 * (Q) + j][nt], 0, 0, 0);              \
  } while (0)

#define BAR       __builtin_amdgcn_s_barrier()
#define WAITLGKM  asm volatile("s_waitcnt lgkmcnt(0)" ::: "memory")
#define WAITVM4   asm volatile("s_waitcnt vmcnt(4)" ::: "memory")
#define WAITVM0   asm volatile("s_waitcnt vmcnt(0)" ::: "memory")
#define PRIO1     __builtin_amdgcn_s_setprio(1)
#define PRIO0     __builtin_amdgcn_s_setprio(0)

static __device__ __forceinline__ void kloop_256(
    const unsigned short* Agl, const unsigned short* Bgl,
    const int lda, const int ldb, const int kiters,   // kiters = K/128 >= 2
    unsigned short* A0s, unsigned short* A1s,
    unsigned short* B0s, unsigned short* B1s,
    const KCtx& c, f32x4 acc[8][4]) {
  short8 bv[4][2], av[2][2];

  // prologue: a(0), b(0), b(1); retire a(0)+b(0), leave b(1) in flight
  STGA(A0s, 0, 0); STGA(A0s, 1, 0);
  STGB(B0s, 0, 0); STGB(B0s, 1, 0);
  STGB(B1s, 0, 64); STGB(B1s, 1, 64);
  WAITVM4;
  BAR;

#pragma unroll 1
  for (int i = 0; i < kiters - 1; ++i) {
    const int k1 = i * 128 + 64, k2 = i * 128 + 128, k3 = i * 128 + 192;
    // P1..P4: tile t0 (A0,B0)
    LDB(B0s); LDA_(A0s, 0); STGA(A1s, 0, k1);
    BAR; WAITLGKM; PRIO1; MM(0); PRIO0; BAR;
    LDA_(A0s, 1); STGA(A1s, 1, k1);
    BAR; WAITLGKM; PRIO1; MM(1); PRIO0; BAR;
    LDA_(A0s, 2); STGB(B0s, 0, k2);
    BAR; WAITLGKM; PRIO1; MM(2); PRIO0; BAR;
    LDA_(A0s, 3); STGB(B0s, 1, k2);
    WAITVM4;
    BAR; WAITLGKM; PRIO1; MM(3); PRIO0; BAR;
    // P5..P8: tile t1 (A1,B1)
    LDB(B1s); LDA_(A1s, 0); STGA(A0s, 0, k2);
    BAR; WAITLGKM; PRIO1; MM(0); PRIO0; BAR;
    LDA_(A1s, 1); STGA(A0s, 1, k2);
    BAR; WAITLGKM; PRIO1; MM(1); PRIO0; BAR;
    LDA_(A1s, 2); STGB(B1s, 0, k3);
    BAR; WAITLGKM; PRIO1; MM(2); PRIO0; BAR;
    LDA_(A1s, 3); STGB(B1s, 1, k3);
    WAITVM4;
    BAR; WAITLGKM; PRIO1; MM(3); PRIO0; BAR;
  }
  // epilogue iteration: tiles 2*kiters-2 (A0,B0), 2*kiters-1 (A1,B1)
  {
    const int kl = (kiters - 1) * 128 + 64;
    LDB(B0s); LDA_(A0s, 0); STGA(A1s, 0, kl);
    BAR; WAITLGKM; PRIO1; MM(0); PRIO0; BAR;
    LDA_(A0s, 1); STGA(A1s, 1, kl);
    BAR; WAITLGKM; PRIO1; MM(1); PRIO0; BAR;
    LDA_(A0s, 2);
    BAR; WAITLGKM; PRIO1; MM(2); PRIO0; BAR;
    LDA_(A0s, 3);
    WAITVM0;                     // drains A1 (needed P5) + leftover B1
    BAR; WAITLGKM; PRIO1; MM(3); PRIO0; BAR;
    LDB(B1s); LDA_(A1s, 0);
    BAR; WAITLGKM; PRIO1; MM(0); PRIO0; BAR;
    LDA_(A1s, 1);
    BAR; WAITLGKM; PRIO1; MM(1); PRIO0; BAR;
    LDA_(A1s, 2);
    BAR; WAITLGKM; PRIO1; MM(2); PRIO0; BAR;
    LDA_(A1s, 3);
    BAR; WAITLGKM; PRIO1; MM(3); PRIO0; BAR;
  }
}

// ===========================================================================
// Epilogue: 16 passes of 16 rows via LDS (fp32, stride 260, <=2-way banks).
// Dual-panel (B0s / B1s alternate, 16x260x4B = 16.6 KB each) -> one
// __syncthreads per pass. ALL acc indices compile-time (rule #20): the pass
// loop is fully unrolled so (P)&7 / (P)&1 are constants.
// Pass P covers C rows [P*16, P*16+16): written by waves with wm == P>>3
// from fragment mt = P&7; read back coalesced by all 512 threads.
// ===========================================================================
#define EPI_W(P) do {                                                         \
    if (c.wm == ((P) >> 3)) {                                                 \
      float* Ep = ((P) & 1) ? pan1 : pan0;                                    \
      _Pragma("unroll") for (int nt = 0; nt < 4; ++nt)                        \
      _Pragma("unroll") for (int r = 0; r < 4; ++r)                           \
        Ep[(c.quad * 4 + r) * 260 + c.wn * 64 + nt * 16 + c.lm] =             \
            acc[(P) & 7][nt][r];                                              \
    }                                                                         \
  } while (0)

#define EPI_R(P) do {                                                         \
    float* Ep = ((P) & 1) ? pan1 : pan0;                                      \
    _Pragma("unroll") for (int j = 0; j < 2; ++j) {                           \
      const int r2 = (tid >> 6) + 8 * j;                                      \
      float4 v = *(const float4*)(Ep + r2 * 260 + (tid & 63) * 4);            \
      if (RELU_BF16) {                                                        \
        ushort4 o;                                                            \
        o.x = f2bf(v.x > 0.f ? v.x : 0.f);                                    \
        o.y = f2bf(v.y > 0.f ? v.y : 0.f);                                    \
        o.z = f2bf(v.z > 0.f ? v.z : 0.f);                                    \
        o.w = f2bf(v.w > 0.f ? v.w : 0.f);                                    \
        *(ushort4*)((unsigned short*)Cout +                                   \
            (size_t)(rowb + (P) * 16 + r2) * ldc + colb + (tid & 63) * 4) = o;\
      } else {                                                                \
        *(float4*)((float*)Cout +                                             \
            (size_t)(rowb + (P) * 16 + r2) * ldc + colb + (tid & 63) * 4) = v;\
      }                                                                       \
    }                                                                         \
  } while (0)

template <bool RELU_BF16>
static __device__ __forceinline__ void epi16(
    unsigned short* B0s, unsigned short* B1s, const KCtx& c, int tid,
    f32x4 acc[8][4], void* Cout, int ldc, int rowb, int colb) {
  float* pan0 = (float*)B0s;
  float* pan1 = (float*)B1s;
  EPI_W(0);  __syncthreads(); EPI_W(1);  EPI_R(0);
  __syncthreads(); EPI_W(2);  EPI_R(1);
  __syncthreads(); EPI_W(3);  EPI_R(2);
  __syncthreads(); EPI_W(4);  EPI_R(3);
  __syncthreads(); EPI_W(5);  EPI_R(4);
  __syncthreads(); EPI_W(6);  EPI_R(5);
  __syncthreads(); EPI_W(7);  EPI_R(6);
  __syncthreads(); EPI_W(8);  EPI_R(7);
  __syncthreads(); EPI_W(9);  EPI_R(8);
  __syncthreads(); EPI_W(10); EPI_R(9);
  __syncthreads(); EPI_W(11); EPI_R(10);
  __syncthreads(); EPI_W(12); EPI_R(11);
  __syncthreads(); EPI_W(13); EPI_R(12);
  __syncthreads(); EPI_W(14); EPI_R(13);
  __syncthreads(); EPI_W(15); EPI_R(14);
  __syncthreads();            EPI_R(15);
}

// ---------------------------------------------------------------------------
// GEMM1: H = relu(x @ W1), M=4096 N=4096 K=2048. grid (16,16) = 256 blocks
// exactly (one full CU round). Output bf16 into A2[:, 2048:].
// ---------------------------------------------------------------------------
__global__ __launch_bounds__(512, 2)
void gemm1(const unsigned short* __restrict__ A,
           const unsigned short* __restrict__ Bt,
           unsigned short* __restrict__ Hout) {
  __shared__ __align__(16) unsigned short A0s[BUF];
  __shared__ __align__(16) unsigned short A1s[BUF];
  __shared__ __align__(16) unsigned short B0s[BUF];
  __shared__ __align__(16) unsigned short B1s[BUF];
  const int tid = threadIdx.x;
  const int lane = tid & 63;
  KCtx c; kctx_init(c, tid);
  const int bm = blockIdx.y, bn = blockIdx.x;
  const int lda = LDA2, ldb = N_IN;
  const int gcol = ((lane & 7) ^ (lane >> 3)) << 3;   // pre-swizzled 16B chunk

  const unsigned short* Agl = A  + (size_t)(bm * 256 + (lane >> 3)) * lda + gcol;
  const unsigned short* Bgl = Bt + (size_t)(bn * 256 + (lane >> 3)) * ldb + gcol;

  f32x4 acc[8][4];
#pragma unroll
  for (int i = 0; i < 8; ++i)
#pragma unroll
    for (int j = 0; j < 4; ++j)
      acc[i][j] = (f32x4){0.f, 0.f, 0.f, 0.f};

  kloop_256(Agl, Bgl, lda, ldb, N_IN / 128, A0s, A1s, B0s, B1s, c, acc);
  __syncthreads();
  epi16<true>(B0s, B1s, c, tid, acc, Hout, LDA2, bm * 256, bn * 256);
}

// ---------------------------------------------------------------------------
// GEMM2: P[z] = A2[:, z*1536:(z+1)*1536] @ W23-slice, z=0..3.
// out = [x|H] @ W[0:6144, 6144:] folded into split-K=4 partials.
// grid (4,16,4) = 256 blocks exactly. Single-writer -> deterministic.
// ---------------------------------------------------------------------------
__global__ __launch_bounds__(512, 2)
void gemm2(const unsigned short* __restrict__ A,
           const unsigned short* __restrict__ Bt,
           float* __restrict__ P) {
  __shared__ __align__(16) unsigned short A0s[BUF];
  __shared__ __align__(16) unsigned short A1s[BUF];
  __shared__ __align__(16) unsigned short B0s[BUF];
  __shared__ __align__(16) unsigned short B1s[BUF];
  const int tid = threadIdx.x;
  const int lane = tid & 63;
  KCtx c; kctx_init(c, tid);
  const int bm = blockIdx.y, bn = blockIdx.x;
  const int ko0 = blockIdx.z * 1536;
  const int lda = LDA2, ldb = LDA2;   // Bt23 is 1024 x 6144
  const int gcol = ((lane & 7) ^ (lane >> 3)) << 3;

  const unsigned short* Agl = A  + (size_t)(bm * 256 + (lane >> 3)) * lda + gcol + ko0;
  const unsigned short* Bgl = Bt + (size_t)(bn * 256 + (lane >> 3)) * ldb + gcol + ko0;

  f32x4 acc[8][4];
#pragma unroll
  for (int i = 0; i < 8; ++i)
#pragma unroll
    for (int j = 0; j < 4; ++j)
      acc[i][j] = (f32x4){0.f, 0.f, 0.f, 0.f};

  kloop_256(Agl, Bgl, lda, ldb, 1536 / 128, A0s, A1s, B0s, B1s, c, acc);
  __syncthreads();
  epi16<false>(B0s, B1s, c, tid, acc, P + (size_t)blockIdx.z * OUT_ELEMS, N_OUT,
               bm * 256, bn * 256);
}

// ---------------------------------------------------------------------------
// kernel_launch
// ws: A2 bf16 4096x6144 (50.3MB) | Bt1 bf16 4096x2048 (16.8MB) |
//     Bt23 bf16 1024x6144 (12.6MB) | P fp32 4 x (4096x1024) (67.1MB) = 146.8MB
// ---------------------------------------------------------------------------
extern "C" void kernel_launch(void* const* d_in, const int* in_sizes, int n_in,
                              void* d_out, int out_size, void* d_ws, size_t ws_size,
                              hipStream_t stream) {
  const float* x = (const float*)d_in[0];
  const float* W = (const float*)d_in[1];

  char* ws = (char*)d_ws;
  const size_t A2_BYTES   = (size_t)BATCH * LDA2 * 2;
  const size_t BT1_BYTES  = (size_t)N_HID * N_IN * 2;
  const size_t BT23_BYTES = (size_t)N_OUT * LDA2 * 2;
  unsigned short* A2   = (unsigned short*)ws;
  unsigned short* Bt1  = (unsigned short*)(ws + A2_BYTES);
  unsigned short* Bt23 = (unsigned short*)(ws + A2_BYTES + BT1_BYTES);
  float*          P    = (float*)(ws + A2_BYTES + BT1_BYTES + BT23_BYTES);

  // 1) x -> bf16 into A2[:, 0:2048]
  conv_x_kernel<<<(BATCH * N_IN / 4) / 256, 256, 0, stream>>>(x, A2);

  // 2) Bt1[n][k] = W[k][2048+n], k<2048, n<4096  (W1^T)
  conv_t_kernel<<<dim3(N_HID / 32, N_IN / 32), 256, 0, stream>>>(
      W + N_IN, N_TOT, Bt1, N_IN);

  // 3) Bt23[n][k] = W[k][6144+n], k<6144, n<1024  (W[0:6144, 6144:]^T)
  conv_t_kernel<<<dim3(N_OUT / 32, LDA2 / 32), 256, 0, stream>>>(
      W + N_IN + N_HID, N_TOT, Bt23, LDA2);

  // 4) H = relu(x @ W1) -> A2[:, 2048:]   (grid 256 exact)
  gemm1<<<dim3(N_HID / 256, BATCH / 256), 512, 0, stream>>>(
      A2, Bt1, A2 + N_IN);

  // 5) P0..P3 = [x|H] @ W23, split-K=4   (grid 256 exact)
  gemm2<<<dim3(N_OUT / 256, BATCH / 256, 4), 512, 0, stream>>>(
      A2, Bt23, P);

  // 6) out = P0 + P1 + P2 + P3
  add4_kernel<<<(OUT_ELEMS / 4) / 256, 256, 0, stream>>>(P, (float*)d_out);
}

// Round 4
// 472.982 us; speedup vs baseline: 1.2079x; 1.0082x over previous
//
#include <hip/hip_runtime.h>
#include <hip/hip_bf16.h>

// Problem constants
#define N_IN  2048
#define N_HID 4096
#define N_OUT 1024
#define N_TOT 7168
#define BATCH 4096
#define LDA2  (N_IN + N_HID)   // 6144: [x | H] activation buffer leading dim
#define OUT_ELEMS ((size_t)BATCH * N_OUT)
#define BUF 16384              // shorts per 256x64 bf16 tile (32 KiB)

typedef __attribute__((ext_vector_type(8))) short short8;
typedef __attribute__((ext_vector_type(4))) float f32x4;

static __device__ __forceinline__ unsigned short f2bf(float f) {
  __hip_bfloat16 h = __float2bfloat16(f);
  return __builtin_bit_cast(unsigned short, h);
}

// ---------------------------------------------------------------------------
// Fused prep kernel (one launch instead of three):
//   blocks [0, 8192):      x (f32) -> bf16 into A2[:, 0:2048]
//   blocks [8192, 16384):  Bt1[n][k]  = W[k][2048+n], k<2048, n<4096  (W1^T)
//   blocks [16384, 22528): Bt23[n][k] = W[k][6144+n], k<6144, n<1024  (W23^T)
// ---------------------------------------------------------------------------
__global__ void prep_kernel(const float* __restrict__ x,
                            const float* __restrict__ W,
                            unsigned short* __restrict__ A2,
                            unsigned short* __restrict__ Bt1,
                            unsigned short* __restrict__ Bt23) {
  __shared__ float tile[32][33];
  const int b = blockIdx.x;
  const int t = threadIdx.x;

  if (b < 8192) {                       // ---- conv_x ----
    int idx = b * 256 + t;
    int row = idx >> 9;                 // N_IN/4 = 512 groups per row
    int col = (idx & 511) << 2;
    const float4 v = *(const float4*)(x + (size_t)row * N_IN + col);
    ushort4 o;
    o.x = f2bf(v.x); o.y = f2bf(v.y); o.z = f2bf(v.z); o.w = f2bf(v.w);
    *(ushort4*)(A2 + (size_t)row * LDA2 + col) = o;
    return;
  }

  // ---- transpose-convert: dst[n][k] = (bf16)src[k][n] ----
  const float* src;
  unsigned short* dst;
  int ldd, bx, by;
  if (b < 16384) {
    const int r0_ = b - 8192;
    bx = r0_ & 127; by = r0_ >> 7;      // n-tiles 128, k-tiles 64
    src = W + N_IN; dst = Bt1; ldd = N_IN;
  } else {
    const int r0_ = b - 16384;
    bx = r0_ & 31; by = r0_ >> 5;       // n-tiles 32, k-tiles 192
    src = W + N_IN + N_HID; dst = Bt23; ldd = LDA2;
  }
  const int k0 = by << 5, n0 = bx << 5;
  const int r = t >> 3, c = (t & 7) << 2;
  const float4 v = *(const float4*)(src + (size_t)(k0 + r) * N_TOT + n0 + c);
  tile[r][c] = v.x; tile[r][c + 1] = v.y; tile[r][c + 2] = v.z; tile[r][c + 3] = v.w;
  __syncthreads();
  ushort4 o;
  o.x = f2bf(tile[c][r]);
  o.y = f2bf(tile[c + 1][r]);
  o.z = f2bf(tile[c + 2][r]);
  o.w = f2bf(tile[c + 3][r]);
  *(ushort4*)(dst + (size_t)(n0 + r) * ldd + k0 + c) = o;
}

// ---------------------------------------------------------------------------
// out = P0 + P1 + P2 + P3 (split-K partials). Fixed order -> deterministic.
// ---------------------------------------------------------------------------
__global__ void add4_kernel(const float* __restrict__ P, float* __restrict__ out) {
  size_t i = ((size_t)blockIdx.x * 256 + threadIdx.x) * 4;
  float4 a = *(const float4*)(P + i);
  float4 b = *(const float4*)(P + OUT_ELEMS + i);
  float4 c = *(const float4*)(P + 2 * OUT_ELEMS + i);
  float4 d = *(const float4*)(P + 3 * OUT_ELEMS + i);
  float4 o;
  o.x = (a.x + b.x) + (c.x + d.x);
  o.y = (a.y + b.y) + (c.y + d.y);
  o.z = (a.z + b.z) + (c.z + d.z);
  o.w = (a.w + b.w) + (c.w + d.w);
  *(float4*)(out + i) = o;
}

// ===========================================================================
// 256x256 / BK=64 / 8-wave (2M x 4N) / 8-phase GEMM (T2+T3+T4+T5).
// All accumulator indices are compile-time constants (rule #20 — the round-2
// runtime-indexed epilogue forced acc[8][4] into scratch: VGPR_Count 120,
// WRITE_SIZE 5x output, MfmaUtil 20%. Round-3 static epilogue fixed it).
//
// Ledger (loads per wave-thread; STG = 2 global_load_lds). Main iter i,
// tiles t0=2i (A0,B0), t1=2i+1 (A1,B1):
//   P1: read B0(all)+A0q0 | STG A1h0@t1
//   P2: read A0q1 | STG A1h1@t1
//   P3: read A0q2 | STG B0h0@t0+2   (B0 reads finished in P1; 2-barrier WAR)
//   P4: read A0q3 | STG B0h1@t0+2; vmcnt(4): outstanding
//       [B1(prev P7/P8), A1(P1/P2), B0(P3/P4)] = 12 -> retires B1+A1 (both
//       consumed at P5), leaves B0's 4 in flight.
//   P5..P8: mirror with A1/B1, staging A0@t0+2, B1@t1+2, vmcnt(4) at P8.
// Epilogue iter: P1/P2 stage A1 only; P4 drains vmcnt(0) -> no in-flight
// DMA after the loop, so all four LDS panels are reusable by the epilogue.
// ===========================================================================
struct KCtx {
  int wave, wm, wn, lm, quad, xr, srow, arow, brow;
};

static __device__ __forceinline__ void kctx_init(KCtx& c, int tid) {
  c.wave = tid >> 6;
  c.wm   = c.wave >> 2;          // 0..1 : 128-row half of C
  c.wn   = c.wave & 3;           // 0..3 : 64-col slice of C
  c.lm   = tid & 15;
  c.quad = (tid & 63) >> 4;
  c.xr   = c.lm & 7;
  c.srow = c.wave * 16;          // staging row base (16 rows per wave)
  c.arow = (c.wm * 128 + c.lm) * 64;
  c.brow = (c.wn * 64  + c.lm) * 64;
}

#define GLDS(GP, LP) __builtin_amdgcn_global_load_lds( \
    (const __attribute__((address_space(1))) void*)(GP), \
    (__attribute__((address_space(3))) void*)(LP), 16, 0, 0)

// Stage half-tile H (128 rows) at k-column KC of the A / B panel.
// Global source is per-lane pre-swizzled (chunk ^= row&7); LDS dest linear.
#define STGA(ARR, H, KC) do {                                                 \
    GLDS(Agl + (size_t)((H)*128 + c.srow    ) * lda + (KC),                   \
         (ARR) + ((H)*128 + c.srow    ) * 64);                                \
    GLDS(Agl + (size_t)((H)*128 + c.srow + 8) * lda + (KC),                   \
         (ARR) + ((H)*128 + c.srow + 8) * 64);                                \
  } while (0)
#define STGB(ARR, H, KC) do {                                                 \
    GLDS(Bgl + (size_t)((H)*128 + c.srow    ) * ldb + (KC),                   \
         (ARR) + ((H)*128 + c.srow    ) * 64);                                \
    GLDS(Bgl + (size_t)((H)*128 + c.srow + 8) * ldb + (KC),                   \
         (ARR) + ((H)*128 + c.srow + 8) * 64);                                \
  } while (0)

#define LDB(BB) do {                                                          \
    _Pragma("unroll") for (int nt = 0; nt < 4; ++nt)                          \
    _Pragma("unroll") for (int kk = 0; kk < 2; ++kk)                          \
      bv[nt][kk] = *(const short8*)((BB) + c.brow + nt * 1024 +               \
                                    (((kk * 4 + c.quad) ^ c.xr) << 3));       \
  } while (0)

#define LDA_(AB, Q) do {                                                      \
    _Pragma("unroll") for (int j = 0; j < 2; ++j)                             \
    _Pragma("unroll") for (int kk = 0; kk < 2; ++kk)                          \
      av[j][kk] = *(const short8*)((AB) + c.arow + (2 * (Q) + j) * 1024 +     \
                                   (((kk * 4 + c.quad) ^ c.xr) << 3));        \
  } while (0)

#define MM(Q) do {                                                            \
    _Pragma("unroll") for (int kk = 0; kk < 2; ++kk)                          \
    _Pragma("unroll") for (int j = 0; j < 2; ++j)                             \
    _Pragma("unroll") for (int nt = 0; nt < 4; ++nt)                          \
      acc[2 * (Q) + j][nt] = __builtin_amdgcn_mfma_f32_16x16x32_bf16(         \
          av[j][kk], bv[nt][kk], acc[2 * (Q) + j][nt], 0, 0, 0);              \
  } while (0)

#define BAR       __builtin_amdgcn_s_barrier()
#define WAITLGKM  asm volatile("s_waitcnt lgkmcnt(0)" ::: "memory")
#define WAITVM4   asm volatile("s_waitcnt vmcnt(4)" ::: "memory")
#define WAITVM0   asm volatile("s_waitcnt vmcnt(0)" ::: "memory")
#define PRIO1     __builtin_amdgcn_s_setprio(1)
#define PRIO0     __builtin_amdgcn_s_setprio(0)

static __device__ __forceinline__ void kloop_256(
    const unsigned short* Agl, const unsigned short* Bgl,
    const int lda, const int ldb, const int kiters,   // kiters = K/128 >= 2
    unsigned short* A0s, unsigned short* A1s,
    unsigned short* B0s, unsigned short* B1s,
    const KCtx& c, f32x4 acc[8][4]) {
  short8 bv[4][2], av[2][2];

  // prologue: a(0), b(0), b(1); retire a(0)+b(0), leave b(1) in flight
  STGA(A0s, 0, 0); STGA(A0s, 1, 0);
  STGB(B0s, 0, 0); STGB(B0s, 1, 0);
  STGB(B1s, 0, 64); STGB(B1s, 1, 64);
  WAITVM4;
  BAR;

#pragma unroll 1
  for (int i = 0; i < kiters - 1; ++i) {
    const int k1 = i * 128 + 64, k2 = i * 128 + 128, k3 = i * 128 + 192;
    // P1..P4: tile t0 (A0,B0)
    LDB(B0s); LDA_(A0s, 0); STGA(A1s, 0, k1);
    BAR; WAITLGKM; PRIO1; MM(0); PRIO0; BAR;
    LDA_(A0s, 1); STGA(A1s, 1, k1);
    BAR; WAITLGKM; PRIO1; MM(1); PRIO0; BAR;
    LDA_(A0s, 2); STGB(B0s, 0, k2);
    BAR; WAITLGKM; PRIO1; MM(2); PRIO0; BAR;
    LDA_(A0s, 3); STGB(B0s, 1, k2);
    WAITVM4;
    BAR; WAITLGKM; PRIO1; MM(3); PRIO0; BAR;
    // P5..P8: tile t1 (A1,B1)
    LDB(B1s); LDA_(A1s, 0); STGA(A0s, 0, k2);
    BAR; WAITLGKM; PRIO1; MM(0); PRIO0; BAR;
    LDA_(A1s, 1); STGA(A0s, 1, k2);
    BAR; WAITLGKM; PRIO1; MM(1); PRIO0; BAR;
    LDA_(A1s, 2); STGB(B1s, 0, k3);
    BAR; WAITLGKM; PRIO1; MM(2); PRIO0; BAR;
    LDA_(A1s, 3); STGB(B1s, 1, k3);
    WAITVM4;
    BAR; WAITLGKM; PRIO1; MM(3); PRIO0; BAR;
  }
  // epilogue iteration: tiles 2*kiters-2 (A0,B0), 2*kiters-1 (A1,B1)
  {
    const int kl = (kiters - 1) * 128 + 64;
    LDB(B0s); LDA_(A0s, 0); STGA(A1s, 0, kl);
    BAR; WAITLGKM; PRIO1; MM(0); PRIO0; BAR;
    LDA_(A0s, 1); STGA(A1s, 1, kl);
    BAR; WAITLGKM; PRIO1; MM(1); PRIO0; BAR;
    LDA_(A0s, 2);
    BAR; WAITLGKM; PRIO1; MM(2); PRIO0; BAR;
    LDA_(A0s, 3);
    WAITVM0;                     // drains A1 (needed P5) + leftover B1
    BAR; WAITLGKM; PRIO1; MM(3); PRIO0; BAR;
    LDB(B1s); LDA_(A1s, 0);
    BAR; WAITLGKM; PRIO1; MM(0); PRIO0; BAR;
    LDA_(A1s, 1);
    BAR; WAITLGKM; PRIO1; MM(1); PRIO0; BAR;
    LDA_(A1s, 2);
    BAR; WAITLGKM; PRIO1; MM(2); PRIO0; BAR;
    LDA_(A1s, 3);
    BAR; WAITLGKM; PRIO1; MM(3); PRIO0; BAR;
  }
}

// ===========================================================================
// Epilogue: 8 passes x 32 rows (16 lo + 16 hi) via LDS, fp32 stride 260.
// ALL 8 waves write each pass (wm=0 -> lo panel, wm=1 -> hi panel), so no
// idle write phases; A-pair / B-pair panels ping-pong -> 1 barrier per pass
// (9 total vs 17 in round 3). All acc indices are macro literals (rule #20).
// Pass P: lo rows [P*16, P*16+16) from frag P of wm=0 waves; hi rows
// [128+P*16, ...) from frag P of wm=1 waves. Read: 512 threads split lo/hi.
// ===========================================================================
#define EPI_W2(P) do {                                                        \
    float* Ep = c.wm ? (((P) & 1) ? panBH : panAH)                            \
                     : (((P) & 1) ? panBL : panAL);                           \
    _Pragma("unroll") for (int nt = 0; nt < 4; ++nt)                          \
    _Pragma("unroll") for (int r = 0; r < 4; ++r)                             \
      Ep[(c.quad * 4 + r) * 260 + c.wn * 64 + nt * 16 + c.lm] =               \
          acc[P][nt][r];                                                      \
  } while (0)

#define EPI_R2(P) do {                                                        \
    float* Ep = grp ? (((P) & 1) ? panBH : panAH)                             \
                    : (((P) & 1) ? panBL : panAL);                            \
    _Pragma("unroll") for (int j = 0; j < 4; ++j) {                           \
      const int r2 = (t8 >> 6) * 4 + j;                                       \
      float4 v = *(const float4*)(Ep + r2 * 260 + (t8 & 63) * 4);             \
      const size_t grow = (size_t)(rowb + grp * 128 + (P) * 16 + r2);         \
      if (RELU_BF16) {                                                        \
        ushort4 o;                                                            \
        o.x = f2bf(v.x > 0.f ? v.x : 0.f);                                    \
        o.y = f2bf(v.y > 0.f ? v.y : 0.f);                                    \
        o.z = f2bf(v.z > 0.f ? v.z : 0.f);                                    \
        o.w = f2bf(v.w > 0.f ? v.w : 0.f);                                    \
        *(ushort4*)((unsigned short*)Cout + grow * ldc + colb +               \
                    (t8 & 63) * 4) = o;                                       \
      } else {                                                                \
        *(float4*)((float*)Cout + grow * ldc + colb + (t8 & 63) * 4) = v;     \
      }                                                                       \
    }                                                                         \
  } while (0)

template <bool RELU_BF16>
static __device__ __forceinline__ void epi8(
    unsigned short* A0s, unsigned short* A1s,
    unsigned short* B0s, unsigned short* B1s,
    const KCtx& c, int tid, f32x4 acc[8][4],
    void* Cout, int ldc, int rowb, int colb) {
  float* panAL = (float*)A0s;   // 16 x 260 f32 = 16.6 KB each (<= 32 KB)
  float* panAH = (float*)A1s;
  float* panBL = (float*)B0s;
  float* panBH = (float*)B1s;
  const int grp = tid >> 8;     // 0: rows 0..127, 1: rows 128..255
  const int t8  = tid & 255;
  EPI_W2(0); __syncthreads();
  EPI_W2(1); EPI_R2(0); __syncthreads();
  EPI_W2(2); EPI_R2(1); __syncthreads();
  EPI_W2(3); EPI_R2(2); __syncthreads();
  EPI_W2(4); EPI_R2(3); __syncthreads();
  EPI_W2(5); EPI_R2(4); __syncthreads();
  EPI_W2(6); EPI_R2(5); __syncthreads();
  EPI_W2(7); EPI_R2(6); __syncthreads();
  EPI_R2(7);
}

// ---------------------------------------------------------------------------
// GEMM1: H = relu(x @ W1), M=4096 N=4096 K=2048. grid (16,16) = 256 blocks
// exactly (one full CU round). Output bf16 into A2[:, 2048:].
// ---------------------------------------------------------------------------
__global__ __launch_bounds__(512, 2)
void gemm1(const unsigned short* __restrict__ A,
           const unsigned short* __restrict__ Bt,
           unsigned short* __restrict__ Hout) {
  __shared__ __align__(16) unsigned short A0s[BUF];
  __shared__ __align__(16) unsigned short A1s[BUF];
  __shared__ __align__(16) unsigned short B0s[BUF];
  __shared__ __align__(16) unsigned short B1s[BUF];
  const int tid = threadIdx.x;
  const int lane = tid & 63;
  KCtx c; kctx_init(c, tid);
  const int bm = blockIdx.y, bn = blockIdx.x;
  const int lda = LDA2, ldb = N_IN;
  const int gcol = ((lane & 7) ^ (lane >> 3)) << 3;   // pre-swizzled 16B chunk

  const unsigned short* Agl = A  + (size_t)(bm * 256 + (lane >> 3)) * lda + gcol;
  const unsigned short* Bgl = Bt + (size_t)(bn * 256 + (lane >> 3)) * ldb + gcol;

  f32x4 acc[8][4];
#pragma unroll
  for (int i = 0; i < 8; ++i)
#pragma unroll
    for (int j = 0; j < 4; ++j)
      acc[i][j] = (f32x4){0.f, 0.f, 0.f, 0.f};

  kloop_256(Agl, Bgl, lda, ldb, N_IN / 128, A0s, A1s, B0s, B1s, c, acc);
  __syncthreads();
  epi8<true>(A0s, A1s, B0s, B1s, c, tid, acc, Hout, LDA2, bm * 256, bn * 256);
}

// ---------------------------------------------------------------------------
// GEMM2: P[z] = A2[:, z*1536:(z+1)*1536] @ W23-slice, z=0..3.
// out = [x|H] @ W[0:6144, 6144:] folded into split-K=4 partials.
// grid (4,16,4) = 256 blocks exactly. Single-writer -> deterministic.
// ---------------------------------------------------------------------------
__global__ __launch_bounds__(512, 2)
void gemm2(const unsigned short* __restrict__ A,
           const unsigned short* __restrict__ Bt,
           float* __restrict__ P) {
  __shared__ __align__(16) unsigned short A0s[BUF];
  __shared__ __align__(16) unsigned short A1s[BUF];
  __shared__ __align__(16) unsigned short B0s[BUF];
  __shared__ __align__(16) unsigned short B1s[BUF];
  const int tid = threadIdx.x;
  const int lane = tid & 63;
  KCtx c; kctx_init(c, tid);
  const int bm = blockIdx.y, bn = blockIdx.x;
  const int ko0 = blockIdx.z * 1536;
  const int lda = LDA2, ldb = LDA2;   // Bt23 is 1024 x 6144
  const int gcol = ((lane & 7) ^ (lane >> 3)) << 3;

  const unsigned short* Agl = A  + (size_t)(bm * 256 + (lane >> 3)) * lda + gcol + ko0;
  const unsigned short* Bgl = Bt + (size_t)(bn * 256 + (lane >> 3)) * ldb + gcol + ko0;

  f32x4 acc[8][4];
#pragma unroll
  for (int i = 0; i < 8; ++i)
#pragma unroll
    for (int j = 0; j < 4; ++j)
      acc[i][j] = (f32x4){0.f, 0.f, 0.f, 0.f};

  kloop_256(Agl, Bgl, lda, ldb, 1536 / 128, A0s, A1s, B0s, B1s, c, acc);
  __syncthreads();
  epi8<false>(A0s, A1s, B0s, B1s, c, tid, acc,
              P + (size_t)blockIdx.z * OUT_ELEMS, N_OUT, bm * 256, bn * 256);
}

// ---------------------------------------------------------------------------
// kernel_launch
// ws: A2 bf16 4096x6144 (50.3MB) | Bt1 bf16 4096x2048 (16.8MB) |
//     Bt23 bf16 1024x6144 (12.6MB) | P fp32 4 x (4096x1024) (67.1MB) = 146.8MB
// ---------------------------------------------------------------------------
extern "C" void kernel_launch(void* const* d_in, const int* in_sizes, int n_in,
                              void* d_out, int out_size, void* d_ws, size_t ws_size,
                              hipStream_t stream) {
  const float* x = (const float*)d_in[0];
  const float* W = (const float*)d_in[1];

  char* ws = (char*)d_ws;
  const size_t A2_BYTES   = (size_t)BATCH * LDA2 * 2;
  const size_t BT1_BYTES  = (size_t)N_HID * N_IN * 2;
  const size_t BT23_BYTES = (size_t)N_OUT * LDA2 * 2;
  unsigned short* A2   = (unsigned short*)ws;
  unsigned short* Bt1  = (unsigned short*)(ws + A2_BYTES);
  unsigned short* Bt23 = (unsigned short*)(ws + A2_BYTES + BT1_BYTES);
  float*          P    = (float*)(ws + A2_BYTES + BT1_BYTES + BT23_BYTES);

  // 1) fused prep: x->bf16, W1^T, W23^T  (8192 + 8192 + 6144 blocks)
  prep_kernel<<<22528, 256, 0, stream>>>(x, W, A2, Bt1, Bt23);

  // 2) H = relu(x @ W1) -> A2[:, 2048:]   (grid 256 exact)
  gemm1<<<dim3(N_HID / 256, BATCH / 256), 512, 0, stream>>>(
      A2, Bt1, A2 + N_IN);

  // 3) P0..P3 = [x|H] @ W23, split-K=4   (grid 256 exact)
  gemm2<<<dim3(N_OUT / 256, BATCH / 256, 4), 512, 0, stream>>>(
      A2, Bt23, P);

  // 4) out = P0 + P1 + P2 + P3
  add4_kernel<<<(OUT_ELEMS / 4) / 256, 256, 0, stream>>>(P, (float*)d_out);
}